// Round 1
// baseline (570.390 us; speedup 1.0000x reference)
//
#include <hip/hip_runtime.h>

#define HID 128
#define NNODES 50000
#define NEDGES 800000

typedef __attribute__((ext_vector_type(8))) short short8;
typedef __attribute__((ext_vector_type(4))) float f32x4;

union U8 { short8 v; unsigned short u[8]; };

__device__ __forceinline__ unsigned short f2b(float f) {
  unsigned int u = __float_as_uint(f);
  u += 0x7FFFu + ((u >> 16) & 1u);
  return (unsigned short)(u >> 16);
}

// ---- pack weights into bf16 fragment-native layout ----
// ws elem[((k>>3)*128 + col)*8 + (k&7)] = bf16(w[k*128 + col])
// segments (bf16 elems): W1p [0,36864) K=288(src 280), W2p [36864,53248) K=128,
// XW1p [53248,69632) K=128, NW1p [69632,102400) K=256, NW2p [102400,118784) K=128
__global__ __launch_bounds__(256) void pack_kernel(
    const float* __restrict__ ew1, const float* __restrict__ ew2,
    const float* __restrict__ xw1, const float* __restrict__ nw1,
    const float* __restrict__ nw2, unsigned short* __restrict__ ws) {
  int i = blockIdx.x * 256 + threadIdx.x;
  const float* w; int base, ksrc;
  if (i < 36864)       { w = ew1; base = 0;      ksrc = 280; }
  else if (i < 53248)  { w = ew2; base = 36864;  ksrc = 128; }
  else if (i < 69632)  { w = xw1; base = 53248;  ksrc = 128; }
  else if (i < 102400) { w = nw1; base = 69632;  ksrc = 256; }
  else if (i < 118784) { w = nw2; base = 102400; ksrc = 128; }
  else return;
  int li = i - base;
  int j = li & 7, t = li >> 3;
  int col = t & 127, kg = t >> 7;
  int k = kg * 8 + j;
  float v = (k < ksrc) ? w[k * 128 + col] : 0.0f;
  ws[i] = f2b(v);
}

// ---- edge kernel: 64 edges/block, 4 waves x 16 rows, 3 chained MFMA GEMMs ----
__global__ __launch_bounds__(256) void edge_kernel(
    const int* __restrict__ src, const int* __restrict__ dst,
    const float* __restrict__ ef, const float* __restrict__ h,
    const float* __restrict__ x,
    const float* __restrict__ eb1, const float* __restrict__ eb2,
    const float* __restrict__ infw, const float* __restrict__ infb,
    const float* __restrict__ xb1, const float* __restrict__ xw2,
    const float* __restrict__ xb2,
    const short8* __restrict__ W1p, const short8* __restrict__ W2p,
    const short8* __restrict__ XW1p,
    float* __restrict__ mi, float* __restrict__ dx) {
  __shared__ __align__(16) char catB[64 * 640];  // cat tile [64][320] bf16, swizzled; later mij tile
  __shared__ __align__(16) char y1B[64 * 256];   // y1 tile [64][128] bf16, swizzled
  __shared__ int dL[64], sL[64];
  __shared__ float relL[64][3];

  const int tid = threadIdx.x;
  const int e0 = blockIdx.x * 64;

  // phase 0: edge meta + edge_feat + gaussian smearing (cols 0..23) + zero pad chunk
  if (tid < 64) {
    int e = e0 + tid;
    int s = src[e], d = dst[e];
    sL[tid] = s; dL[tid] = d;
    float rx = x[3*d+0] - x[3*s+0];
    float ry = x[3*d+1] - x[3*s+1];
    float rz = x[3*d+2] - x[3*s+2];
    relL[tid][0] = rx; relL[tid][1] = ry; relL[tid][2] = rz;
    float r = rx*rx + ry*ry + rz*rz;
    float vals[24];
    const float4 efv = reinterpret_cast<const float4*>(ef)[e];
    vals[0]=efv.x; vals[1]=efv.y; vals[2]=efv.z; vals[3]=efv.w;
    const float step = 100.0f / 19.0f;
    const float co = -0.5f / (step * step);
    #pragma unroll
    for (int g = 0; g < 20; ++g) {
      float t = r - (float)g * step;
      vals[4+g] = __expf(co * t * t);
    }
    #pragma unroll
    for (int c = 0; c < 3; ++c) {
      U8 u;
      #pragma unroll
      for (int j = 0; j < 8; ++j) u.u[j] = f2b(vals[c*8+j]);
      *reinterpret_cast<short8*>(catB + tid*640 + ((c ^ (tid&7))<<4)) = u.v;
    }
    U8 z;
    #pragma unroll
    for (int j = 0; j < 8; ++j) z.u[j] = 0;
    *reinterpret_cast<short8*>(catB + tid*640 + ((35 ^ (tid&7))<<4)) = z.v;  // cols 280..287
  }
  __syncthreads();

  // phase 1: gather h[dst] (chunks 3..18) and h[src] (chunks 19..34)
  for (int i = tid; i < 64*32; i += 256) {
    int row = i >> 5, c = i & 31;
    int node = (c < 16) ? dL[row] : sL[row];
    const float4* hp = reinterpret_cast<const float4*>(h + node*128 + (c&15)*8);
    float4 a = hp[0], b = hp[1];
    U8 u;
    u.u[0]=f2b(a.x); u.u[1]=f2b(a.y); u.u[2]=f2b(a.z); u.u[3]=f2b(a.w);
    u.u[4]=f2b(b.x); u.u[5]=f2b(b.y); u.u[6]=f2b(b.z); u.u[7]=f2b(b.w);
    int chunk = 3 + c;
    *reinterpret_cast<short8*>(catB + row*640 + ((chunk ^ (row&7))<<4)) = u.v;
  }
  __syncthreads();

  const int lane = tid & 63, wave = tid >> 6;
  const int lr = lane & 15, lg = lane >> 4;
  const int rb = wave * 16;
  const int arow = rb + lr;

  // GEMM1: y1 = relu(cat @ W1 + eb1), K=288
  f32x4 acc[8];
  #pragma unroll
  for (int nt = 0; nt < 8; ++nt) acc[nt] = (f32x4)0.0f;
  #pragma unroll
  for (int kt = 0; kt < 9; ++kt) {
    int chunk = kt*4 + lg;
    short8 a = *reinterpret_cast<const short8*>(catB + arow*640 + ((chunk ^ (arow&7))<<4));
    const short8* bp = W1p + chunk*128 + lr;
    #pragma unroll
    for (int nt = 0; nt < 8; ++nt)
      acc[nt] = __builtin_amdgcn_mfma_f32_16x16x32_bf16(a, bp[nt*16], acc[nt], 0, 0, 0);
  }
  #pragma unroll
  for (int nt = 0; nt < 8; ++nt) {
    int col = nt*16 + lr;
    float bias = eb1[col];
    #pragma unroll
    for (int r = 0; r < 4; ++r) {
      int row = rb + lg*4 + r;
      float v = fmaxf(acc[nt][r] + bias, 0.f);
      *reinterpret_cast<unsigned short*>(y1B + row*256 + (((col>>3) ^ (row&7))<<4) + ((col&7)<<1)) = f2b(v);
    }
  }

  // GEMM2: mij = relu(y1 @ W2 + eb2), K=128
  f32x4 acc2[8];
  #pragma unroll
  for (int nt = 0; nt < 8; ++nt) acc2[nt] = (f32x4)0.0f;
  #pragma unroll
  for (int kt = 0; kt < 4; ++kt) {
    int chunk = kt*4 + lg;
    short8 a = *reinterpret_cast<const short8*>(y1B + arow*256 + ((chunk ^ (arow&7))<<4));
    const short8* bp = W2p + chunk*128 + lr;
    #pragma unroll
    for (int nt = 0; nt < 8; ++nt)
      acc2[nt] = __builtin_amdgcn_mfma_f32_16x16x32_bf16(a, bp[nt*16], acc2[nt], 0, 0, 0);
  }
  float mval[8][4];
  float p[4] = {0.f, 0.f, 0.f, 0.f};
  #pragma unroll
  for (int nt = 0; nt < 8; ++nt) {
    int col = nt*16 + lr;
    float bias = eb2[col];
    float wi = infw[col];
    #pragma unroll
    for (int r = 0; r < 4; ++r) {
      int row = rb + lg*4 + r;
      float v = fmaxf(acc2[nt][r] + bias, 0.f);
      mval[nt][r] = v;
      p[r] += v * wi;
      // write mij bf16 into catB (this wave's rows only; cat no longer needed)
      *reinterpret_cast<unsigned short*>(catB + row*640 + (((col>>3) ^ (row&7))<<4) + ((col&7)<<1)) = f2b(v);
    }
  }
  #pragma unroll
  for (int m = 1; m < 16; m <<= 1) {
    #pragma unroll
    for (int r = 0; r < 4; ++r) p[r] += __shfl_xor(p[r], m, 64);
  }
  float ib = infb[0];
  float ev[4];
  #pragma unroll
  for (int r = 0; r < 4; ++r) ev[r] = 1.f / (1.f + __expf(-(p[r] + ib)));

  // scatter mi[dst] += mij * eij
  #pragma unroll
  for (int r = 0; r < 4; ++r) {
    int row = rb + lg*4 + r;
    int d = dL[row];
    float e = ev[r];
    #pragma unroll
    for (int nt = 0; nt < 8; ++nt) {
      int col = nt*16 + lr;
      atomicAdd(&mi[d*128 + col], mval[nt][r] * e);
    }
  }

  // GEMM3: y2 = relu(mij @ XW1 + xb1); x_scale = y2 . xw2 + xb2
  f32x4 acc3[8];
  #pragma unroll
  for (int nt = 0; nt < 8; ++nt) acc3[nt] = (f32x4)0.0f;
  #pragma unroll
  for (int kt = 0; kt < 4; ++kt) {
    int chunk = kt*4 + lg;
    short8 a = *reinterpret_cast<const short8*>(catB + arow*640 + ((chunk ^ (arow&7))<<4));
    const short8* bp = XW1p + chunk*128 + lr;
    #pragma unroll
    for (int nt = 0; nt < 8; ++nt)
      acc3[nt] = __builtin_amdgcn_mfma_f32_16x16x32_bf16(a, bp[nt*16], acc3[nt], 0, 0, 0);
  }
  float q[4] = {0.f, 0.f, 0.f, 0.f};
  #pragma unroll
  for (int nt = 0; nt < 8; ++nt) {
    int col = nt*16 + lr;
    float bias = xb1[col];
    float w2 = xw2[col];
    #pragma unroll
    for (int r = 0; r < 4; ++r) {
      float v = fmaxf(acc3[nt][r] + bias, 0.f);
      q[r] += v * w2;
    }
  }
  #pragma unroll
  for (int m = 1; m < 16; m <<= 1) {
    #pragma unroll
    for (int r = 0; r < 4; ++r) q[r] += __shfl_xor(q[r], m, 64);
  }
  float xbv = xb2[0];
  if (lr < 3) {
    #pragma unroll
    for (int r = 0; r < 4; ++r) {
      int row = rb + lg*4 + r;
      atomicAdd(&dx[dL[row]*3 + lr], relL[row][lr] * (q[r] + xbv));
    }
  }
}

// ---- node kernel: h_new = h + MLP([mi,h]); x_new = x + dx ----
__global__ __launch_bounds__(256) void node_kernel(
    const float* __restrict__ h, const float* __restrict__ x,
    const float* __restrict__ nb1, const float* __restrict__ nb2,
    const short8* __restrict__ NW1p, const short8* __restrict__ NW2p,
    float* __restrict__ out) {
  __shared__ __align__(16) char c2B[64 * 512];  // [64][256] bf16, swizzled
  __shared__ __align__(16) char y3B[64 * 256];  // [64][128] bf16, swizzled
  const int tid = threadIdx.x;
  const int n0 = blockIdx.x * 64;
  const float* mi = out;

  for (int i = tid; i < 64*32; i += 256) {
    int row = i >> 5, c = i & 31;
    int node = n0 + row;
    U8 u;
    if (node < NNODES) {
      const float4* p = (c < 16)
        ? reinterpret_cast<const float4*>(mi + node*128 + c*8)
        : reinterpret_cast<const float4*>(h + node*128 + (c-16)*8);
      float4 a = p[0], b = p[1];
      u.u[0]=f2b(a.x); u.u[1]=f2b(a.y); u.u[2]=f2b(a.z); u.u[3]=f2b(a.w);
      u.u[4]=f2b(b.x); u.u[5]=f2b(b.y); u.u[6]=f2b(b.z); u.u[7]=f2b(b.w);
    } else {
      #pragma unroll
      for (int j = 0; j < 8; ++j) u.u[j] = 0;
    }
    *reinterpret_cast<short8*>(c2B + row*512 + ((c ^ (row&7))<<4)) = u.v;
  }
  __syncthreads();

  const int lane = tid & 63, wave = tid >> 6;
  const int lr = lane & 15, lg = lane >> 4;
  const int rb = wave * 16;
  const int arow = rb + lr;

  // GEMM n1: y3 = relu([mi,h] @ NW1 + nb1), K=256
  f32x4 acc[8];
  #pragma unroll
  for (int nt = 0; nt < 8; ++nt) acc[nt] = (f32x4)0.0f;
  #pragma unroll
  for (int kt = 0; kt < 8; ++kt) {
    int chunk = kt*4 + lg;
    short8 a = *reinterpret_cast<const short8*>(c2B + arow*512 + ((chunk ^ (arow&7))<<4));
    const short8* bp = NW1p + chunk*128 + lr;
    #pragma unroll
    for (int nt = 0; nt < 8; ++nt)
      acc[nt] = __builtin_amdgcn_mfma_f32_16x16x32_bf16(a, bp[nt*16], acc[nt], 0, 0, 0);
  }
  #pragma unroll
  for (int nt = 0; nt < 8; ++nt) {
    int col = nt*16 + lr;
    float bias = nb1[col];
    #pragma unroll
    for (int r = 0; r < 4; ++r) {
      int row = rb + lg*4 + r;
      float v = fmaxf(acc[nt][r] + bias, 0.f);
      *reinterpret_cast<unsigned short*>(y3B + row*256 + (((col>>3) ^ (row&7))<<4) + ((col&7)<<1)) = f2b(v);
    }
  }

  // GEMM n2: out = y3 @ NW2 + nb2 + h, K=128
  f32x4 acc2[8];
  #pragma unroll
  for (int nt = 0; nt < 8; ++nt) acc2[nt] = (f32x4)0.0f;
  #pragma unroll
  for (int kt = 0; kt < 4; ++kt) {
    int chunk = kt*4 + lg;
    short8 a = *reinterpret_cast<const short8*>(y3B + arow*256 + ((chunk ^ (arow&7))<<4));
    const short8* bp = NW2p + chunk*128 + lr;
    #pragma unroll
    for (int nt = 0; nt < 8; ++nt)
      acc2[nt] = __builtin_amdgcn_mfma_f32_16x16x32_bf16(a, bp[nt*16], acc2[nt], 0, 0, 0);
  }
  #pragma unroll
  for (int nt = 0; nt < 8; ++nt) {
    int col = nt*16 + lr;
    float b2 = nb2[col];
    #pragma unroll
    for (int r = 0; r < 4; ++r) {
      int row = rb + lg*4 + r;
      int node = n0 + row;
      if (node < NNODES) {
        int idx = node*128 + col;
        out[idx] = acc2[nt][r] + b2 + h[idx];
      }
    }
  }

  // x_new = x + delta (delta already accumulated in out's x-region)
  if (tid < 192) {
    int node = n0 + tid/3;
    if (node < NNODES) {
      int idx = node*3 + (tid%3);
      float* xo = out + NNODES*HID;
      xo[idx] = x[idx] + xo[idx];
    }
  }
}

extern "C" void kernel_launch(void* const* d_in, const int* in_sizes, int n_in,
                              void* d_out, int out_size, void* d_ws, size_t ws_size,
                              hipStream_t stream) {
  const int*   src  = (const int*)  d_in[0];
  const int*   dst  = (const int*)  d_in[1];
  const float* ef   = (const float*)d_in[2];
  const float* h    = (const float*)d_in[3];
  const float* x    = (const float*)d_in[4];
  const float* ew1  = (const float*)d_in[5];
  const float* eb1  = (const float*)d_in[6];
  const float* ew2  = (const float*)d_in[7];
  const float* eb2  = (const float*)d_in[8];
  const float* infw = (const float*)d_in[9];
  const float* infb = (const float*)d_in[10];
  const float* xw1  = (const float*)d_in[11];
  const float* xb1  = (const float*)d_in[12];
  const float* xw2  = (const float*)d_in[13];
  const float* xb2  = (const float*)d_in[14];
  const float* nw1  = (const float*)d_in[15];
  const float* nb1  = (const float*)d_in[16];
  const float* nw2  = (const float*)d_in[17];
  const float* nb2  = (const float*)d_in[18];

  float* out = (float*)d_out;
  float* mi  = out;                  // mi accumulates where h_new will go
  float* dxp = out + NNODES*HID;     // delta_x accumulates where x_new will go
  unsigned short* wsp = (unsigned short*)d_ws;

  hipMemsetAsync(d_out, 0, (size_t)out_size * sizeof(float), stream);

  pack_kernel<<<464, 256, 0, stream>>>(ew1, ew2, xw1, nw1, nw2, wsp);

  edge_kernel<<<NEDGES/64, 256, 0, stream>>>(
      src, dst, ef, h, x, eb1, eb2, infw, infb, xb1, xw2, xb2,
      (const short8*)wsp, (const short8*)(wsp + 36864), (const short8*)(wsp + 53248),
      mi, dxp);

  node_kernel<<<(NNODES + 63)/64, 256, 0, stream>>>(
      h, x, nb1, nb2,
      (const short8*)(wsp + 69632), (const short8*)(wsp + 102400),
      out);
}

// Round 2
// 460.188 us; speedup vs baseline: 1.2395x; 1.2395x over previous
//
#include <hip/hip_runtime.h>

#define HID 128
#define NNODES 50000
#define NEDGES 800000

typedef __attribute__((ext_vector_type(8))) short short8;
typedef __attribute__((ext_vector_type(4))) float f32x4;
typedef __attribute__((ext_vector_type(2))) short short2v;

#if defined(__has_builtin)
#if __has_builtin(__builtin_amdgcn_global_atomic_fadd_v2bf16)
#define HAS_PK_BF16 1
#endif
#endif
#ifndef HAS_PK_BF16
#define HAS_PK_BF16 0
#endif

union U8 { short8 v; unsigned short u[8]; };

__device__ __forceinline__ unsigned short f2b(float f) {
  unsigned int u = __float_as_uint(f);
  u += 0x7FFFu + ((u >> 16) & 1u);
  return (unsigned short)(u >> 16);
}

// ---- pack weights into bf16 fragment-native layout ----
// ws elem[((k>>3)*128 + col)*8 + (k&7)] = bf16(w[k*128 + col])
// segments (bf16 elems): W1p [0,36864) K=288(src 280), W2p [36864,53248) K=128,
// XW1p [53248,69632) K=128, NW1p [69632,102400) K=256, NW2p [102400,118784) K=128
__global__ __launch_bounds__(256) void pack_kernel(
    const float* __restrict__ ew1, const float* __restrict__ ew2,
    const float* __restrict__ xw1, const float* __restrict__ nw1,
    const float* __restrict__ nw2, unsigned short* __restrict__ ws) {
  int i = blockIdx.x * 256 + threadIdx.x;
  const float* w; int base, ksrc;
  if (i < 36864)       { w = ew1; base = 0;      ksrc = 280; }
  else if (i < 53248)  { w = ew2; base = 36864;  ksrc = 128; }
  else if (i < 69632)  { w = xw1; base = 53248;  ksrc = 128; }
  else if (i < 102400) { w = nw1; base = 69632;  ksrc = 256; }
  else if (i < 118784) { w = nw2; base = 102400; ksrc = 128; }
  else return;
  int li = i - base;
  int j = li & 7, t = li >> 3;
  int col = t & 127, kg = t >> 7;
  int k = kg * 8 + j;
  float v = (k < ksrc) ? w[k * 128 + col] : 0.0f;
  ws[i] = f2b(v);
}

// ---- edge kernel v2: 64 edges/block, N-split waves (each wave: all 64 rows x 32 cols) ----
// cat tile [64][288] bf16 in LDS, row stride 576 B.
// zone A chunks 0..31 swizzled c^(row&7); zone B chunks 32..35 swizzled 32+((c&3)^(row&3)).
// After GEMM1 (barrier): y1 lives in zone chunks 0..15, mij in chunks 16..31.
template<int MIBF16>
__global__ __launch_bounds__(256, 4) void edge_kernel(
    const int* __restrict__ src, const int* __restrict__ dst,
    const float* __restrict__ ef, const float* __restrict__ h,
    const float* __restrict__ x,
    const float* __restrict__ eb1, const float* __restrict__ eb2,
    const float* __restrict__ infw, const float* __restrict__ infb,
    const float* __restrict__ xb1, const float* __restrict__ xw2,
    const float* __restrict__ xb2,
    const short8* __restrict__ W1p, const short8* __restrict__ W2p,
    const short8* __restrict__ XW1p,
    float* __restrict__ miF, unsigned short* __restrict__ miB,
    float* __restrict__ dx) {
  __shared__ __align__(16) char catB[64 * 576];
  __shared__ int dL[64], sL[64];
  __shared__ float relL[64][3];
  __shared__ float ppart[4][64];   // reused as qpart after sync2
  __shared__ float eijL[64];

  const int tid = threadIdx.x;
  const int e0 = blockIdx.x * 64;

  // phase 0: edge meta + edge_feat + gaussian smearing (chunks 0..2) + zero pad chunk 35
  if (tid < 64) {
    int e = e0 + tid;
    int s = src[e], d = dst[e];
    sL[tid] = s; dL[tid] = d;
    float rx = x[3*d+0] - x[3*s+0];
    float ry = x[3*d+1] - x[3*s+1];
    float rz = x[3*d+2] - x[3*s+2];
    relL[tid][0] = rx; relL[tid][1] = ry; relL[tid][2] = rz;
    float r = rx*rx + ry*ry + rz*rz;
    float vals[24];
    const float4 efv = reinterpret_cast<const float4*>(ef)[e];
    vals[0]=efv.x; vals[1]=efv.y; vals[2]=efv.z; vals[3]=efv.w;
    const float step = 100.0f / 19.0f;
    const float co = -0.5f / (step * step);
    #pragma unroll
    for (int g = 0; g < 20; ++g) {
      float t = r - (float)g * step;
      vals[4+g] = __expf(co * t * t);
    }
    #pragma unroll
    for (int c = 0; c < 3; ++c) {
      U8 u;
      #pragma unroll
      for (int j = 0; j < 8; ++j) u.u[j] = f2b(vals[c*8+j]);
      *reinterpret_cast<short8*>(catB + tid*576 + ((c ^ (tid&7))<<4)) = u.v;
    }
    U8 z;
    #pragma unroll
    for (int j = 0; j < 8; ++j) z.u[j] = 0;
    *reinterpret_cast<short8*>(catB + tid*576 + ((32 + (3 ^ (tid&3)))<<4)) = z.v;
  }
  __syncthreads();

  // phase 1: gather h[dst] (chunks 3..18) and h[src] (chunks 19..34)
  for (int i = tid; i < 64*32; i += 256) {
    int row = i >> 5, c = i & 31;
    int node = (c < 16) ? dL[row] : sL[row];
    const float4* hp = reinterpret_cast<const float4*>(h + node*128 + (c&15)*8);
    float4 a = hp[0], b = hp[1];
    U8 u;
    u.u[0]=f2b(a.x); u.u[1]=f2b(a.y); u.u[2]=f2b(a.z); u.u[3]=f2b(a.w);
    u.u[4]=f2b(b.x); u.u[5]=f2b(b.y); u.u[6]=f2b(b.z); u.u[7]=f2b(b.w);
    int chunk = 3 + c;
    int sw = (chunk < 32) ? (chunk ^ (row&7)) : (32 + ((chunk&3) ^ (row&3)));
    *reinterpret_cast<short8*>(catB + row*576 + (sw<<4)) = u.v;
  }
  __syncthreads();

  const int lane = tid & 63, w = tid >> 6;
  const int lr = lane & 15, lg = lane >> 4;
  const int l7 = lr & 7, l3 = lr & 3;
  const int colb = w*32 + lr;  // col for j=0; j=1 adds 16

  // ---- GEMM1: y1 = relu(cat @ W1 + eb1), K=288 ----
  f32x4 acc[4][2];
  #pragma unroll
  for (int t = 0; t < 4; ++t) { acc[t][0] = (f32x4)0.0f; acc[t][1] = (f32x4)0.0f; }
  #pragma unroll
  for (int kt = 0; kt < 9; ++kt) {
    int ch = (kt < 8) ? ((kt*4+lg) ^ l7) : (32 + (lg ^ l3));
    short8 a0 = *reinterpret_cast<const short8*>(catB + (0*16+lr)*576 + (ch<<4));
    short8 a1 = *reinterpret_cast<const short8*>(catB + (1*16+lr)*576 + (ch<<4));
    short8 a2 = *reinterpret_cast<const short8*>(catB + (2*16+lr)*576 + (ch<<4));
    short8 a3 = *reinterpret_cast<const short8*>(catB + (3*16+lr)*576 + (ch<<4));
    short8 b0 = W1p[(kt*4+lg)*128 + colb];
    short8 b1 = W1p[(kt*4+lg)*128 + colb + 16];
    acc[0][0] = __builtin_amdgcn_mfma_f32_16x16x32_bf16(a0, b0, acc[0][0], 0, 0, 0);
    acc[0][1] = __builtin_amdgcn_mfma_f32_16x16x32_bf16(a0, b1, acc[0][1], 0, 0, 0);
    acc[1][0] = __builtin_amdgcn_mfma_f32_16x16x32_bf16(a1, b0, acc[1][0], 0, 0, 0);
    acc[1][1] = __builtin_amdgcn_mfma_f32_16x16x32_bf16(a1, b1, acc[1][1], 0, 0, 0);
    acc[2][0] = __builtin_amdgcn_mfma_f32_16x16x32_bf16(a2, b0, acc[2][0], 0, 0, 0);
    acc[2][1] = __builtin_amdgcn_mfma_f32_16x16x32_bf16(a2, b1, acc[2][1], 0, 0, 0);
    acc[3][0] = __builtin_amdgcn_mfma_f32_16x16x32_bf16(a3, b0, acc[3][0], 0, 0, 0);
    acc[3][1] = __builtin_amdgcn_mfma_f32_16x16x32_bf16(a3, b1, acc[3][1], 0, 0, 0);
  }
  __syncthreads();  // all cat reads complete before y1 overwrites zone A

  {
    float be0 = eb1[colb], be1 = eb1[colb+16];
    #pragma unroll
    for (int t = 0; t < 4; ++t)
      #pragma unroll
      for (int j = 0; j < 2; ++j) {
        float bias = j ? be1 : be0;
        int col = w*32 + j*16 + lr;
        #pragma unroll
        for (int rg = 0; rg < 4; ++rg) {
          int row = t*16 + lg*4 + rg;
          float v = fmaxf(acc[t][j][rg] + bias, 0.f);
          int chunk = (col>>3) ^ (row&7);
          *reinterpret_cast<unsigned short*>(catB + row*576 + (chunk<<4) + ((col&7)<<1)) = f2b(v);
        }
      }
  }
  __syncthreads();  // y1 visible to all waves

  // ---- GEMM2: mij = relu(y1 @ W2 + eb2), K=128 ----
  f32x4 acc2[4][2];
  #pragma unroll
  for (int t = 0; t < 4; ++t) { acc2[t][0] = (f32x4)0.0f; acc2[t][1] = (f32x4)0.0f; }
  #pragma unroll
  for (int kt = 0; kt < 4; ++kt) {
    int ch = (kt*4+lg) ^ l7;
    short8 a0 = *reinterpret_cast<const short8*>(catB + (0*16+lr)*576 + (ch<<4));
    short8 a1 = *reinterpret_cast<const short8*>(catB + (1*16+lr)*576 + (ch<<4));
    short8 a2 = *reinterpret_cast<const short8*>(catB + (2*16+lr)*576 + (ch<<4));
    short8 a3 = *reinterpret_cast<const short8*>(catB + (3*16+lr)*576 + (ch<<4));
    short8 b0 = W2p[(kt*4+lg)*128 + colb];
    short8 b1 = W2p[(kt*4+lg)*128 + colb + 16];
    acc2[0][0] = __builtin_amdgcn_mfma_f32_16x16x32_bf16(a0, b0, acc2[0][0], 0, 0, 0);
    acc2[0][1] = __builtin_amdgcn_mfma_f32_16x16x32_bf16(a0, b1, acc2[0][1], 0, 0, 0);
    acc2[1][0] = __builtin_amdgcn_mfma_f32_16x16x32_bf16(a1, b0, acc2[1][0], 0, 0, 0);
    acc2[1][1] = __builtin_amdgcn_mfma_f32_16x16x32_bf16(a1, b1, acc2[1][1], 0, 0, 0);
    acc2[2][0] = __builtin_amdgcn_mfma_f32_16x16x32_bf16(a2, b0, acc2[2][0], 0, 0, 0);
    acc2[2][1] = __builtin_amdgcn_mfma_f32_16x16x32_bf16(a2, b1, acc2[2][1], 0, 0, 0);
    acc2[3][0] = __builtin_amdgcn_mfma_f32_16x16x32_bf16(a3, b0, acc2[3][0], 0, 0, 0);
    acc2[3][1] = __builtin_amdgcn_mfma_f32_16x16x32_bf16(a3, b1, acc2[3][1], 0, 0, 0);
  }
  // epilogue: mval kept in acc2, mij -> LDS chunks 16..31, per-lane inf partials
  {
    float be0 = eb2[colb], be1 = eb2[colb+16];
    float iw0 = infw[colb], iw1 = infw[colb+16];
    float pl[4][4];
    #pragma unroll
    for (int t = 0; t < 4; ++t)
      #pragma unroll
      for (int rg = 0; rg < 4; ++rg) pl[t][rg] = 0.f;
    #pragma unroll
    for (int t = 0; t < 4; ++t)
      #pragma unroll
      for (int j = 0; j < 2; ++j) {
        float bias = j ? be1 : be0;
        float iw = j ? iw1 : iw0;
        int col = w*32 + j*16 + lr;
        #pragma unroll
        for (int rg = 0; rg < 4; ++rg) {
          int row = t*16 + lg*4 + rg;
          float v = fmaxf(acc2[t][j][rg] + bias, 0.f);
          acc2[t][j][rg] = v;
          pl[t][rg] += v * iw;
          int chunk = 16 + (((col>>3)&15) ^ (row&7));
          *reinterpret_cast<unsigned short*>(catB + row*576 + (chunk<<4) + ((col&7)<<1)) = f2b(v);
        }
      }
    #pragma unroll
    for (int m = 1; m < 16; m <<= 1)
      #pragma unroll
      for (int t = 0; t < 4; ++t)
        #pragma unroll
        for (int rg = 0; rg < 4; ++rg) pl[t][rg] += __shfl_xor(pl[t][rg], m, 64);
    if (lr == 0) {
      #pragma unroll
      for (int t = 0; t < 4; ++t)
        #pragma unroll
        for (int rg = 0; rg < 4; ++rg) ppart[w][t*16 + lg*4 + rg] = pl[t][rg];
    }
  }
  __syncthreads();  // sync1: mij + ppart ready

  if (tid < 64) {
    float s = ppart[0][tid] + ppart[1][tid] + ppart[2][tid] + ppart[3][tid] + infb[0];
    eijL[tid] = 1.f / (1.f + __expf(-s));
  }
  __syncthreads();  // sync2: eijL ready

  // ---- scatter mi[dst] += mij * eij ----
  #pragma unroll
  for (int t = 0; t < 4; ++t)
    #pragma unroll
    for (int rg = 0; rg < 4; ++rg) {
      int row = t*16 + lg*4 + rg;
      int d = dL[row];
      float e = eijL[row];
      float u0 = acc2[t][0][rg] * e;
      float u1 = acc2[t][1][rg] * e;
      if (MIBF16) {
        float got = __shfl_xor((lr & 1) ? u0 : u1, 1, 64);
        int col0; unsigned short lo, hi;
        if (!(lr & 1)) { col0 = w*32 + lr;          lo = f2b(u0);  hi = f2b(got); }
        else           { col0 = w*32 + 16 + lr - 1; lo = f2b(got); hi = f2b(u1); }
        short2v pv; pv[0] = (short)lo; pv[1] = (short)hi;
#if HAS_PK_BF16
        __builtin_amdgcn_global_atomic_fadd_v2bf16(
            (__attribute__((address_space(1))) short2v*)(miB + d*128 + col0), pv);
#endif
      } else {
        atomicAdd(miF + d*128 + colb,      u0);
        atomicAdd(miF + d*128 + colb + 16, u1);
      }
    }

  // ---- GEMM3: y2 = relu(mij @ XW1 + xb1); x_scale = y2 . xw2 + xb2 ----
  f32x4 acc3[4][2];
  #pragma unroll
  for (int t = 0; t < 4; ++t) { acc3[t][0] = (f32x4)0.0f; acc3[t][1] = (f32x4)0.0f; }
  #pragma unroll
  for (int kt = 0; kt < 4; ++kt) {
    int ch = 16 + ((kt*4+lg) ^ l7);
    short8 a0 = *reinterpret_cast<const short8*>(catB + (0*16+lr)*576 + (ch<<4));
    short8 a1 = *reinterpret_cast<const short8*>(catB + (1*16+lr)*576 + (ch<<4));
    short8 a2 = *reinterpret_cast<const short8*>(catB + (2*16+lr)*576 + (ch<<4));
    short8 a3 = *reinterpret_cast<const short8*>(catB + (3*16+lr)*576 + (ch<<4));
    short8 b0 = XW1p[(kt*4+lg)*128 + colb];
    short8 b1 = XW1p[(kt*4+lg)*128 + colb + 16];
    acc3[0][0] = __builtin_amdgcn_mfma_f32_16x16x32_bf16(a0, b0, acc3[0][0], 0, 0, 0);
    acc3[0][1] = __builtin_amdgcn_mfma_f32_16x16x32_bf16(a0, b1, acc3[0][1], 0, 0, 0);
    acc3[1][0] = __builtin_amdgcn_mfma_f32_16x16x32_bf16(a1, b0, acc3[1][0], 0, 0, 0);
    acc3[1][1] = __builtin_amdgcn_mfma_f32_16x16x32_bf16(a1, b1, acc3[1][1], 0, 0, 0);
    acc3[2][0] = __builtin_amdgcn_mfma_f32_16x16x32_bf16(a2, b0, acc3[2][0], 0, 0, 0);
    acc3[2][1] = __builtin_amdgcn_mfma_f32_16x16x32_bf16(a2, b1, acc3[2][1], 0, 0, 0);
    acc3[3][0] = __builtin_amdgcn_mfma_f32_16x16x32_bf16(a3, b0, acc3[3][0], 0, 0, 0);
    acc3[3][1] = __builtin_amdgcn_mfma_f32_16x16x32_bf16(a3, b1, acc3[3][1], 0, 0, 0);
  }
  {
    float bx0 = xb1[colb], bx1 = xb1[colb+16];
    float xwv0 = xw2[colb], xwv1 = xw2[colb+16];
    float ql[4][4];
    #pragma unroll
    for (int t = 0; t < 4; ++t)
      #pragma unroll
      for (int rg = 0; rg < 4; ++rg) ql[t][rg] = 0.f;
    #pragma unroll
    for (int t = 0; t < 4; ++t)
      #pragma unroll
      for (int j = 0; j < 2; ++j) {
        float bias = j ? bx1 : bx0;
        float xwv = j ? xwv1 : xwv0;
        #pragma unroll
        for (int rg = 0; rg < 4; ++rg) {
          float v = fmaxf(acc3[t][j][rg] + bias, 0.f);
          ql[t][rg] += v * xwv;
        }
      }
    #pragma unroll
    for (int m = 1; m < 16; m <<= 1)
      #pragma unroll
      for (int t = 0; t < 4; ++t)
        #pragma unroll
        for (int rg = 0; rg < 4; ++rg) ql[t][rg] += __shfl_xor(ql[t][rg], m, 64);
    if (lr == 0) {
      #pragma unroll
      for (int t = 0; t < 4; ++t)
        #pragma unroll
        for (int rg = 0; rg < 4; ++rg) ppart[w][t*16 + lg*4 + rg] = ql[t][rg];
    }
  }
  __syncthreads();  // sync3: qpart ready

  if (tid < 192) {
    int row = tid / 3, c = tid - row*3;
    float q = ppart[0][row] + ppart[1][row] + ppart[2][row] + ppart[3][row] + xb2[0];
    atomicAdd(dx + dL[row]*3 + c, relL[row][c] * q);
  }
}

// ---- node kernel: h_new = h + MLP([mi,h]); x_new = x + dx ----
template<int MIBF16>
__global__ __launch_bounds__(256) void node_kernel(
    const float* __restrict__ h, const float* __restrict__ x,
    const float* __restrict__ nb1, const float* __restrict__ nb2,
    const short8* __restrict__ NW1p, const short8* __restrict__ NW2p,
    const unsigned short* __restrict__ miB,
    float* __restrict__ out) {
  __shared__ __align__(16) char c2B[64 * 512];  // [64][256] bf16, swizzled
  __shared__ __align__(16) char y3B[64 * 256];  // [64][128] bf16, swizzled
  const int tid = threadIdx.x;
  const int n0 = blockIdx.x * 64;
  const float* mi = out;

  for (int i = tid; i < 64*32; i += 256) {
    int row = i >> 5, c = i & 31;
    int node = n0 + row;
    U8 u;
    if (node < NNODES) {
      if (c < 16 && MIBF16) {
        u.v = *reinterpret_cast<const short8*>(miB + node*128 + c*8);
      } else {
        const float4* p = (c < 16)
          ? reinterpret_cast<const float4*>(mi + node*128 + c*8)
          : reinterpret_cast<const float4*>(h + node*128 + (c-16)*8);
        float4 a = p[0], b = p[1];
        u.u[0]=f2b(a.x); u.u[1]=f2b(a.y); u.u[2]=f2b(a.z); u.u[3]=f2b(a.w);
        u.u[4]=f2b(b.x); u.u[5]=f2b(b.y); u.u[6]=f2b(b.z); u.u[7]=f2b(b.w);
      }
    } else {
      #pragma unroll
      for (int j = 0; j < 8; ++j) u.u[j] = 0;
    }
    *reinterpret_cast<short8*>(c2B + row*512 + ((c ^ (row&7))<<4)) = u.v;
  }
  __syncthreads();

  const int lane = tid & 63, wave = tid >> 6;
  const int lr = lane & 15, lg = lane >> 4;
  const int rb = wave * 16;
  const int arow = rb + lr;

  // GEMM n1: y3 = relu([mi,h] @ NW1 + nb1), K=256
  f32x4 acc[8];
  #pragma unroll
  for (int nt = 0; nt < 8; ++nt) acc[nt] = (f32x4)0.0f;
  #pragma unroll
  for (int kt = 0; kt < 8; ++kt) {
    int chunk = kt*4 + lg;
    short8 a = *reinterpret_cast<const short8*>(c2B + arow*512 + ((chunk ^ (arow&7))<<4));
    const short8* bp = NW1p + chunk*128 + lr;
    #pragma unroll
    for (int nt = 0; nt < 8; ++nt)
      acc[nt] = __builtin_amdgcn_mfma_f32_16x16x32_bf16(a, bp[nt*16], acc[nt], 0, 0, 0);
  }
  #pragma unroll
  for (int nt = 0; nt < 8; ++nt) {
    int col = nt*16 + lr;
    float bias = nb1[col];
    #pragma unroll
    for (int r = 0; r < 4; ++r) {
      int row = rb + lg*4 + r;
      float v = fmaxf(acc[nt][r] + bias, 0.f);
      *reinterpret_cast<unsigned short*>(y3B + row*256 + (((col>>3) ^ (row&7))<<4) + ((col&7)<<1)) = f2b(v);
    }
  }

  // GEMM n2: out = y3 @ NW2 + nb2 + h, K=128
  f32x4 acc2[8];
  #pragma unroll
  for (int nt = 0; nt < 8; ++nt) acc2[nt] = (f32x4)0.0f;
  #pragma unroll
  for (int kt = 0; kt < 4; ++kt) {
    int chunk = kt*4 + lg;
    short8 a = *reinterpret_cast<const short8*>(y3B + arow*256 + ((chunk ^ (arow&7))<<4));
    const short8* bp = NW2p + chunk*128 + lr;
    #pragma unroll
    for (int nt = 0; nt < 8; ++nt)
      acc2[nt] = __builtin_amdgcn_mfma_f32_16x16x32_bf16(a, bp[nt*16], acc2[nt], 0, 0, 0);
  }
  __syncthreads();  // ensure all mi reads (MIBF16=0 path reads out) done before overwrite
  #pragma unroll
  for (int nt = 0; nt < 8; ++nt) {
    int col = nt*16 + lr;
    float b2 = nb2[col];
    #pragma unroll
    for (int r = 0; r < 4; ++r) {
      int row = rb + lg*4 + r;
      int node = n0 + row;
      if (node < NNODES) {
        int idx = node*128 + col;
        out[idx] = acc2[nt][r] + b2 + h[idx];
      }
    }
  }

  if (tid < 192) {
    int node = n0 + tid/3;
    if (node < NNODES) {
      int idx = node*3 + (tid%3);
      float* xo = out + NNODES*HID;
      xo[idx] = x[idx] + xo[idx];
    }
  }
}

extern "C" void kernel_launch(void* const* d_in, const int* in_sizes, int n_in,
                              void* d_out, int out_size, void* d_ws, size_t ws_size,
                              hipStream_t stream) {
  const int*   src  = (const int*)  d_in[0];
  const int*   dst  = (const int*)  d_in[1];
  const float* ef   = (const float*)d_in[2];
  const float* h    = (const float*)d_in[3];
  const float* x    = (const float*)d_in[4];
  const float* ew1  = (const float*)d_in[5];
  const float* eb1  = (const float*)d_in[6];
  const float* ew2  = (const float*)d_in[7];
  const float* eb2  = (const float*)d_in[8];
  const float* infw = (const float*)d_in[9];
  const float* infb = (const float*)d_in[10];
  const float* xw1  = (const float*)d_in[11];
  const float* xb1  = (const float*)d_in[12];
  const float* xw2  = (const float*)d_in[13];
  const float* xb2  = (const float*)d_in[14];
  const float* nw1  = (const float*)d_in[15];
  const float* nb1  = (const float*)d_in[16];
  const float* nw2  = (const float*)d_in[17];
  const float* nb2  = (const float*)d_in[18];

  float* out = (float*)d_out;
  float* miF = out;                  // f32 path: mi accumulates where h_new will go
  float* dxp = out + NNODES*HID;     // delta_x accumulates where x_new will go
  unsigned short* wsp = (unsigned short*)d_ws;
  unsigned short* miB = wsp + 118784;

  size_t need = 118784u*2u + (size_t)NNODES*HID*2u;
  int mib = (HAS_PK_BF16 && ws_size >= need) ? 1 : 0;

  if (mib) {
    hipMemsetAsync(miB, 0, (size_t)NNODES*HID*2, stream);
    hipMemsetAsync(dxp, 0, (size_t)NNODES*3*4, stream);
  } else {
    hipMemsetAsync(d_out, 0, (size_t)out_size * sizeof(float), stream);
  }

  pack_kernel<<<464, 256, 0, stream>>>(ew1, ew2, xw1, nw1, nw2, wsp);

  if (mib) {
    edge_kernel<1><<<NEDGES/64, 256, 0, stream>>>(
        src, dst, ef, h, x, eb1, eb2, infw, infb, xb1, xw2, xb2,
        (const short8*)wsp, (const short8*)(wsp + 36864), (const short8*)(wsp + 53248),
        miF, miB, dxp);
    node_kernel<1><<<(NNODES + 63)/64, 256, 0, stream>>>(
        h, x, nb1, nb2,
        (const short8*)(wsp + 69632), (const short8*)(wsp + 102400), miB, out);
  } else {
    edge_kernel<0><<<NEDGES/64, 256, 0, stream>>>(
        src, dst, ef, h, x, eb1, eb2, infw, infb, xb1, xw2, xb2,
        (const short8*)wsp, (const short8*)(wsp + 36864), (const short8*)(wsp + 53248),
        miF, miB, dxp);
    node_kernel<0><<<(NNODES + 63)/64, 256, 0, stream>>>(
        h, x, nb1, nb2,
        (const short8*)(wsp + 69632), (const short8*)(wsp + 102400), miB, out);
  }
}

// Round 3
// 354.074 us; speedup vs baseline: 1.6109x; 1.2997x over previous
//
#include <hip/hip_runtime.h>

#define HID 128
#define NNODES 50000
#define NEDGES 800000

typedef __attribute__((ext_vector_type(8))) short short8;
typedef __attribute__((ext_vector_type(4))) float f32x4;

union U8 { short8 v; unsigned short u[8]; };

__device__ __forceinline__ unsigned short f2b(float f) {
  unsigned int u = __float_as_uint(f);
  u += 0x7FFFu + ((u >> 16) & 1u);
  return (unsigned short)(u >> 16);
}

// packed bf16 atomic add: mem[addr] += lo, mem[addr+2] += hi  (gfx950 ISA)
__device__ __forceinline__ void atomicPkAddBf16(unsigned short* addr, unsigned int packed) {
  asm volatile("global_atomic_pk_add_bf16 %0, %1, off" :: "v"(addr), "v"(packed) : "memory");
}

// ---- pack weights into bf16 fragment-native layout ----
// ws elem[((k>>3)*128 + col)*8 + (k&7)] = bf16(w[k*128 + col])
// segments (bf16 elems): W1p [0,36864) K=288(src 280), W2p [36864,53248) K=128,
// XW1p [53248,69632) K=128, NW1p [69632,102400) K=256, NW2p [102400,118784) K=128
__global__ __launch_bounds__(256) void pack_kernel(
    const float* __restrict__ ew1, const float* __restrict__ ew2,
    const float* __restrict__ xw1, const float* __restrict__ nw1,
    const float* __restrict__ nw2, unsigned short* __restrict__ ws) {
  int i = blockIdx.x * 256 + threadIdx.x;
  const float* w; int base, ksrc;
  if (i < 36864)       { w = ew1; base = 0;      ksrc = 280; }
  else if (i < 53248)  { w = ew2; base = 36864;  ksrc = 128; }
  else if (i < 69632)  { w = xw1; base = 53248;  ksrc = 128; }
  else if (i < 102400) { w = nw1; base = 69632;  ksrc = 256; }
  else if (i < 118784) { w = nw2; base = 102400; ksrc = 128; }
  else return;
  int li = i - base;
  int j = li & 7, t = li >> 3;
  int col = t & 127, kg = t >> 7;
  int k = kg * 8 + j;
  float v = (k < ksrc) ? w[k * 128 + col] : 0.0f;
  ws[i] = f2b(v);
}

// ---- edge kernel: 64 edges/block, N-split waves (each wave: all 64 rows x 32 cols) ----
// cat tile [64][288] bf16 in LDS, row stride 576 B.
// zone A chunks 0..31 swizzled c^(row&7); zone B chunks 32..35 swizzled 32+((c&3)^(row&3)).
// After GEMM1 (barrier): y1 lives in chunks 0..15, mij in chunks 16..31.
template<int MIBF16>
__global__ __launch_bounds__(256, 4) void edge_kernel(
    const int* __restrict__ src, const int* __restrict__ dst,
    const float* __restrict__ ef, const float* __restrict__ h,
    const float* __restrict__ x,
    const float* __restrict__ eb1, const float* __restrict__ eb2,
    const float* __restrict__ infw, const float* __restrict__ infb,
    const float* __restrict__ xb1, const float* __restrict__ xw2,
    const float* __restrict__ xb2,
    const short8* __restrict__ W1p, const short8* __restrict__ W2p,
    const short8* __restrict__ XW1p,
    float* __restrict__ miF, unsigned short* __restrict__ miB,
    float* __restrict__ dx) {
  __shared__ __align__(16) char catB[64 * 576];
  __shared__ int dL[64], sL[64];
  __shared__ float relL[64][3];
  __shared__ float ppart[4][64];   // reused as qpart after sync2
  __shared__ float eijL[64];

  const int tid = threadIdx.x;
  const int e0 = blockIdx.x * 64;

  // phase 0: edge meta + edge_feat + gaussian smearing (chunks 0..2) + zero pad chunk
  if (tid < 64) {
    int e = e0 + tid;
    int s = src[e], d = dst[e];
    sL[tid] = s; dL[tid] = d;
    float rx = x[3*d+0] - x[3*s+0];
    float ry = x[3*d+1] - x[3*s+1];
    float rz = x[3*d+2] - x[3*s+2];
    relL[tid][0] = rx; relL[tid][1] = ry; relL[tid][2] = rz;
    float r = rx*rx + ry*ry + rz*rz;
    float vals[24];
    const float4 efv = reinterpret_cast<const float4*>(ef)[e];
    vals[0]=efv.x; vals[1]=efv.y; vals[2]=efv.z; vals[3]=efv.w;
    const float step = 100.0f / 19.0f;
    const float co = -0.5f / (step * step);
    #pragma unroll
    for (int g = 0; g < 20; ++g) {
      float t = r - (float)g * step;
      vals[4+g] = __expf(co * t * t);
    }
    #pragma unroll
    for (int c = 0; c < 3; ++c) {
      U8 u;
      #pragma unroll
      for (int j = 0; j < 8; ++j) u.u[j] = f2b(vals[c*8+j]);
      *reinterpret_cast<short8*>(catB + tid*576 + ((c ^ (tid&7))<<4)) = u.v;
    }
    U8 z;
    #pragma unroll
    for (int j = 0; j < 8; ++j) z.u[j] = 0;
    *reinterpret_cast<short8*>(catB + tid*576 + ((32 + (3 ^ (tid&3)))<<4)) = z.v;
  }
  __syncthreads();

  // phase 1: gather h[dst] (chunks 3..18) and h[src] (chunks 19..34)
  for (int i = tid; i < 64*32; i += 256) {
    int row = i >> 5, c = i & 31;
    int node = (c < 16) ? dL[row] : sL[row];
    const float4* hp = reinterpret_cast<const float4*>(h + node*128 + (c&15)*8);
    float4 a = hp[0], b = hp[1];
    U8 u;
    u.u[0]=f2b(a.x); u.u[1]=f2b(a.y); u.u[2]=f2b(a.z); u.u[3]=f2b(a.w);
    u.u[4]=f2b(b.x); u.u[5]=f2b(b.y); u.u[6]=f2b(b.z); u.u[7]=f2b(b.w);
    int chunk = 3 + c;
    int sw = (chunk < 32) ? (chunk ^ (row&7)) : (32 + ((chunk&3) ^ (row&3)));
    *reinterpret_cast<short8*>(catB + row*576 + (sw<<4)) = u.v;
  }
  __syncthreads();

  const int lane = tid & 63, w = tid >> 6;
  const int lr = lane & 15, lg = lane >> 4;
  const int l7 = lr & 7, l3 = lr & 3;
  const int colb = w*32 + lr;  // col for j=0; j=1 adds 16

  // ---- GEMM1: y1 = relu(cat @ W1 + eb1), K=288 ----
  f32x4 acc[4][2];
  #pragma unroll
  for (int t = 0; t < 4; ++t) { acc[t][0] = (f32x4)0.0f; acc[t][1] = (f32x4)0.0f; }
  #pragma unroll
  for (int kt = 0; kt < 9; ++kt) {
    int ch = (kt < 8) ? ((kt*4+lg) ^ l7) : (32 + (lg ^ l3));
    short8 a0 = *reinterpret_cast<const short8*>(catB + (0*16+lr)*576 + (ch<<4));
    short8 a1 = *reinterpret_cast<const short8*>(catB + (1*16+lr)*576 + (ch<<4));
    short8 a2 = *reinterpret_cast<const short8*>(catB + (2*16+lr)*576 + (ch<<4));
    short8 a3 = *reinterpret_cast<const short8*>(catB + (3*16+lr)*576 + (ch<<4));
    short8 b0 = W1p[(kt*4+lg)*128 + colb];
    short8 b1 = W1p[(kt*4+lg)*128 + colb + 16];
    acc[0][0] = __builtin_amdgcn_mfma_f32_16x16x32_bf16(a0, b0, acc[0][0], 0, 0, 0);
    acc[0][1] = __builtin_amdgcn_mfma_f32_16x16x32_bf16(a0, b1, acc[0][1], 0, 0, 0);
    acc[1][0] = __builtin_amdgcn_mfma_f32_16x16x32_bf16(a1, b0, acc[1][0], 0, 0, 0);
    acc[1][1] = __builtin_amdgcn_mfma_f32_16x16x32_bf16(a1, b1, acc[1][1], 0, 0, 0);
    acc[2][0] = __builtin_amdgcn_mfma_f32_16x16x32_bf16(a2, b0, acc[2][0], 0, 0, 0);
    acc[2][1] = __builtin_amdgcn_mfma_f32_16x16x32_bf16(a2, b1, acc[2][1], 0, 0, 0);
    acc[3][0] = __builtin_amdgcn_mfma_f32_16x16x32_bf16(a3, b0, acc[3][0], 0, 0, 0);
    acc[3][1] = __builtin_amdgcn_mfma_f32_16x16x32_bf16(a3, b1, acc[3][1], 0, 0, 0);
  }
  __syncthreads();  // all cat reads complete before y1 overwrites zone A

  {
    float be0 = eb1[colb], be1 = eb1[colb+16];
    #pragma unroll
    for (int t = 0; t < 4; ++t)
      #pragma unroll
      for (int j = 0; j < 2; ++j) {
        float bias = j ? be1 : be0;
        int col = w*32 + j*16 + lr;
        #pragma unroll
        for (int rg = 0; rg < 4; ++rg) {
          int row = t*16 + lg*4 + rg;
          float v = fmaxf(acc[t][j][rg] + bias, 0.f);
          int chunk = (col>>3) ^ (row&7);
          *reinterpret_cast<unsigned short*>(catB + row*576 + (chunk<<4) + ((col&7)<<1)) = f2b(v);
        }
      }
  }
  __syncthreads();  // y1 visible to all waves

  // ---- GEMM2: mij = relu(y1 @ W2 + eb2), K=128 ----
  f32x4 acc2[4][2];
  #pragma unroll
  for (int t = 0; t < 4; ++t) { acc2[t][0] = (f32x4)0.0f; acc2[t][1] = (f32x4)0.0f; }
  #pragma unroll
  for (int kt = 0; kt < 4; ++kt) {
    int ch = (kt*4+lg) ^ l7;
    short8 a0 = *reinterpret_cast<const short8*>(catB + (0*16+lr)*576 + (ch<<4));
    short8 a1 = *reinterpret_cast<const short8*>(catB + (1*16+lr)*576 + (ch<<4));
    short8 a2 = *reinterpret_cast<const short8*>(catB + (2*16+lr)*576 + (ch<<4));
    short8 a3 = *reinterpret_cast<const short8*>(catB + (3*16+lr)*576 + (ch<<4));
    short8 b0 = W2p[(kt*4+lg)*128 + colb];
    short8 b1 = W2p[(kt*4+lg)*128 + colb + 16];
    acc2[0][0] = __builtin_amdgcn_mfma_f32_16x16x32_bf16(a0, b0, acc2[0][0], 0, 0, 0);
    acc2[0][1] = __builtin_amdgcn_mfma_f32_16x16x32_bf16(a0, b1, acc2[0][1], 0, 0, 0);
    acc2[1][0] = __builtin_amdgcn_mfma_f32_16x16x32_bf16(a1, b0, acc2[1][0], 0, 0, 0);
    acc2[1][1] = __builtin_amdgcn_mfma_f32_16x16x32_bf16(a1, b1, acc2[1][1], 0, 0, 0);
    acc2[2][0] = __builtin_amdgcn_mfma_f32_16x16x32_bf16(a2, b0, acc2[2][0], 0, 0, 0);
    acc2[2][1] = __builtin_amdgcn_mfma_f32_16x16x32_bf16(a2, b1, acc2[2][1], 0, 0, 0);
    acc2[3][0] = __builtin_amdgcn_mfma_f32_16x16x32_bf16(a3, b0, acc2[3][0], 0, 0, 0);
    acc2[3][1] = __builtin_amdgcn_mfma_f32_16x16x32_bf16(a3, b1, acc2[3][1], 0, 0, 0);
  }
  // epilogue: mval kept in acc2, mij -> LDS chunks 16..31, per-lane inf partials
  {
    float be0 = eb2[colb], be1 = eb2[colb+16];
    float iw0 = infw[colb], iw1 = infw[colb+16];
    float pl[4][4];
    #pragma unroll
    for (int t = 0; t < 4; ++t)
      #pragma unroll
      for (int rg = 0; rg < 4; ++rg) pl[t][rg] = 0.f;
    #pragma unroll
    for (int t = 0; t < 4; ++t)
      #pragma unroll
      for (int j = 0; j < 2; ++j) {
        float bias = j ? be1 : be0;
        float iw = j ? iw1 : iw0;
        int col = w*32 + j*16 + lr;
        #pragma unroll
        for (int rg = 0; rg < 4; ++rg) {
          int row = t*16 + lg*4 + rg;
          float v = fmaxf(acc2[t][j][rg] + bias, 0.f);
          acc2[t][j][rg] = v;
          pl[t][rg] += v * iw;
          int chunk = 16 + (((col>>3)&15) ^ (row&7));
          *reinterpret_cast<unsigned short*>(catB + row*576 + (chunk<<4) + ((col&7)<<1)) = f2b(v);
        }
      }
    #pragma unroll
    for (int m = 1; m < 16; m <<= 1)
      #pragma unroll
      for (int t = 0; t < 4; ++t)
        #pragma unroll
        for (int rg = 0; rg < 4; ++rg) pl[t][rg] += __shfl_xor(pl[t][rg], m, 64);
    if (lr == 0) {
      #pragma unroll
      for (int t = 0; t < 4; ++t)
        #pragma unroll
        for (int rg = 0; rg < 4; ++rg) ppart[w][t*16 + lg*4 + rg] = pl[t][rg];
    }
  }
  __syncthreads();  // sync1: mij + ppart ready

  if (tid < 64) {
    float s = ppart[0][tid] + ppart[1][tid] + ppart[2][tid] + ppart[3][tid] + infb[0];
    eijL[tid] = 1.f / (1.f + __expf(-s));
  }
  __syncthreads();  // sync2: eijL ready

  // ---- scatter mi[dst] += mij * eij ----
  #pragma unroll
  for (int t = 0; t < 4; ++t)
    #pragma unroll
    for (int rg = 0; rg < 4; ++rg) {
      int row = t*16 + lg*4 + rg;
      int d = dL[row];
      float e = eijL[row];
      float u0 = acc2[t][0][rg] * e;
      float u1 = acc2[t][1][rg] * e;
      if (MIBF16) {
        // pair adjacent cols across lane^1, one packed-bf16 atomic per pair
        float got = __shfl_xor((lr & 1) ? u0 : u1, 1, 64);
        int col0; unsigned short lo, hi;
        if (!(lr & 1)) { col0 = w*32 + lr;          lo = f2b(u0);  hi = f2b(got); }
        else           { col0 = w*32 + 16 + lr - 1; lo = f2b(got); hi = f2b(u1); }
        unsigned int packed = (unsigned int)lo | ((unsigned int)hi << 16);
        atomicPkAddBf16(miB + d*128 + col0, packed);
      } else {
        atomicAdd(miF + d*128 + colb,      u0);
        atomicAdd(miF + d*128 + colb + 16, u1);
      }
    }

  // ---- GEMM3: y2 = relu(mij @ XW1 + xb1); x_scale = y2 . xw2 + xb2 ----
  f32x4 acc3[4][2];
  #pragma unroll
  for (int t = 0; t < 4; ++t) { acc3[t][0] = (f32x4)0.0f; acc3[t][1] = (f32x4)0.0f; }
  #pragma unroll
  for (int kt = 0; kt < 4; ++kt) {
    int ch = 16 + ((kt*4+lg) ^ l7);
    short8 a0 = *reinterpret_cast<const short8*>(catB + (0*16+lr)*576 + (ch<<4));
    short8 a1 = *reinterpret_cast<const short8*>(catB + (1*16+lr)*576 + (ch<<4));
    short8 a2 = *reinterpret_cast<const short8*>(catB + (2*16+lr)*576 + (ch<<4));
    short8 a3 = *reinterpret_cast<const short8*>(catB + (3*16+lr)*576 + (ch<<4));
    short8 b0 = XW1p[(kt*4+lg)*128 + colb];
    short8 b1 = XW1p[(kt*4+lg)*128 + colb + 16];
    acc3[0][0] = __builtin_amdgcn_mfma_f32_16x16x32_bf16(a0, b0, acc3[0][0], 0, 0, 0);
    acc3[0][1] = __builtin_amdgcn_mfma_f32_16x16x32_bf16(a0, b1, acc3[0][1], 0, 0, 0);
    acc3[1][0] = __builtin_amdgcn_mfma_f32_16x16x32_bf16(a1, b0, acc3[1][0], 0, 0, 0);
    acc3[1][1] = __builtin_amdgcn_mfma_f32_16x16x32_bf16(a1, b1, acc3[1][1], 0, 0, 0);
    acc3[2][0] = __builtin_amdgcn_mfma_f32_16x16x32_bf16(a2, b0, acc3[2][0], 0, 0, 0);
    acc3[2][1] = __builtin_amdgcn_mfma_f32_16x16x32_bf16(a2, b1, acc3[2][1], 0, 0, 0);
    acc3[3][0] = __builtin_amdgcn_mfma_f32_16x16x32_bf16(a3, b0, acc3[3][0], 0, 0, 0);
    acc3[3][1] = __builtin_amdgcn_mfma_f32_16x16x32_bf16(a3, b1, acc3[3][1], 0, 0, 0);
  }
  {
    float bx0 = xb1[colb], bx1 = xb1[colb+16];
    float xwv0 = xw2[colb], xwv1 = xw2[colb+16];
    float ql[4][4];
    #pragma unroll
    for (int t = 0; t < 4; ++t)
      #pragma unroll
      for (int rg = 0; rg < 4; ++rg) ql[t][rg] = 0.f;
    #pragma unroll
    for (int t = 0; t < 4; ++t)
      #pragma unroll
      for (int j = 0; j < 2; ++j) {
        float bias = j ? bx1 : bx0;
        float xwv = j ? xwv1 : xwv0;
        #pragma unroll
        for (int rg = 0; rg < 4; ++rg) {
          float v = fmaxf(acc3[t][j][rg] + bias, 0.f);
          ql[t][rg] += v * xwv;
        }
      }
    #pragma unroll
    for (int m = 1; m < 16; m <<= 1)
      #pragma unroll
      for (int t = 0; t < 4; ++t)
        #pragma unroll
        for (int rg = 0; rg < 4; ++rg) ql[t][rg] += __shfl_xor(ql[t][rg], m, 64);
    if (lr == 0) {
      #pragma unroll
      for (int t = 0; t < 4; ++t)
        #pragma unroll
        for (int rg = 0; rg < 4; ++rg) ppart[w][t*16 + lg*4 + rg] = ql[t][rg];
    }
  }
  __syncthreads();  // sync3: qpart ready

  if (tid < 192) {
    int row = tid / 3, c = tid - row*3;
    float q = ppart[0][row] + ppart[1][row] + ppart[2][row] + ppart[3][row] + xb2[0];
    atomicAdd(dx + dL[row]*3 + c, relL[row][c] * q);
  }
}

// ---- node kernel: h_new = h + MLP([mi,h]); x_new = x + dx ----
template<int MIBF16>
__global__ __launch_bounds__(256) void node_kernel(
    const float* __restrict__ h, const float* __restrict__ x,
    const float* __restrict__ nb1, const float* __restrict__ nb2,
    const short8* __restrict__ NW1p, const short8* __restrict__ NW2p,
    const unsigned short* __restrict__ miB,
    float* __restrict__ out) {
  __shared__ __align__(16) char c2B[64 * 512];  // [64][256] bf16, swizzled
  __shared__ __align__(16) char y3B[64 * 256];  // [64][128] bf16, swizzled
  const int tid = threadIdx.x;
  const int n0 = blockIdx.x * 64;
  const float* mi = out;

  for (int i = tid; i < 64*32; i += 256) {
    int row = i >> 5, c = i & 31;
    int node = n0 + row;
    U8 u;
    if (node < NNODES) {
      if (c < 16 && MIBF16) {
        u.v = *reinterpret_cast<const short8*>(miB + node*128 + c*8);
      } else {
        const float4* p = (c < 16)
          ? reinterpret_cast<const float4*>(mi + node*128 + c*8)
          : reinterpret_cast<const float4*>(h + node*128 + (c-16)*8);
        float4 a = p[0], b = p[1];
        u.u[0]=f2b(a.x); u.u[1]=f2b(a.y); u.u[2]=f2b(a.z); u.u[3]=f2b(a.w);
        u.u[4]=f2b(b.x); u.u[5]=f2b(b.y); u.u[6]=f2b(b.z); u.u[7]=f2b(b.w);
      }
    } else {
      #pragma unroll
      for (int j = 0; j < 8; ++j) u.u[j] = 0;
    }
    *reinterpret_cast<short8*>(c2B + row*512 + ((c ^ (row&7))<<4)) = u.v;
  }
  __syncthreads();

  const int lane = tid & 63, wave = tid >> 6;
  const int lr = lane & 15, lg = lane >> 4;
  const int rb = wave * 16;
  const int arow = rb + lr;

  // GEMM n1: y3 = relu([mi,h] @ NW1 + nb1), K=256
  f32x4 acc[8];
  #pragma unroll
  for (int nt = 0; nt < 8; ++nt) acc[nt] = (f32x4)0.0f;
  #pragma unroll
  for (int kt = 0; kt < 8; ++kt) {
    int chunk = kt*4 + lg;
    short8 a = *reinterpret_cast<const short8*>(c2B + arow*512 + ((chunk ^ (arow&7))<<4));
    const short8* bp = NW1p + chunk*128 + lr;
    #pragma unroll
    for (int nt = 0; nt < 8; ++nt)
      acc[nt] = __builtin_amdgcn_mfma_f32_16x16x32_bf16(a, bp[nt*16], acc[nt], 0, 0, 0);
  }
  #pragma unroll
  for (int nt = 0; nt < 8; ++nt) {
    int col = nt*16 + lr;
    float bias = nb1[col];
    #pragma unroll
    for (int r = 0; r < 4; ++r) {
      int row = rb + lg*4 + r;
      float v = fmaxf(acc[nt][r] + bias, 0.f);
      *reinterpret_cast<unsigned short*>(y3B + row*256 + (((col>>3) ^ (row&7))<<4) + ((col&7)<<1)) = f2b(v);
    }
  }

  // GEMM n2: out = y3 @ NW2 + nb2 + h, K=128
  f32x4 acc2[8];
  #pragma unroll
  for (int nt = 0; nt < 8; ++nt) acc2[nt] = (f32x4)0.0f;
  #pragma unroll
  for (int kt = 0; kt < 4; ++kt) {
    int chunk = kt*4 + lg;
    short8 a = *reinterpret_cast<const short8*>(y3B + arow*256 + ((chunk ^ (arow&7))<<4));
    const short8* bp = NW2p + chunk*128 + lr;
    #pragma unroll
    for (int nt = 0; nt < 8; ++nt)
      acc2[nt] = __builtin_amdgcn_mfma_f32_16x16x32_bf16(a, bp[nt*16], acc2[nt], 0, 0, 0);
  }
  __syncthreads();  // ensure all mi reads (MIBF16=0 path reads out) done before overwrite
  #pragma unroll
  for (int nt = 0; nt < 8; ++nt) {
    int col = nt*16 + lr;
    float b2 = nb2[col];
    #pragma unroll
    for (int r = 0; r < 4; ++r) {
      int row = rb + lg*4 + r;
      int node = n0 + row;
      if (node < NNODES) {
        int idx = node*128 + col;
        out[idx] = acc2[nt][r] + b2 + h[idx];
      }
    }
  }

  if (tid < 192) {
    int node = n0 + tid/3;
    if (node < NNODES) {
      int idx = node*3 + (tid%3);
      float* xo = out + NNODES*HID;
      xo[idx] = x[idx] + xo[idx];
    }
  }
}

extern "C" void kernel_launch(void* const* d_in, const int* in_sizes, int n_in,
                              void* d_out, int out_size, void* d_ws, size_t ws_size,
                              hipStream_t stream) {
  const int*   src  = (const int*)  d_in[0];
  const int*   dst  = (const int*)  d_in[1];
  const float* ef   = (const float*)d_in[2];
  const float* h    = (const float*)d_in[3];
  const float* x    = (const float*)d_in[4];
  const float* ew1  = (const float*)d_in[5];
  const float* eb1  = (const float*)d_in[6];
  const float* ew2  = (const float*)d_in[7];
  const float* eb2  = (const float*)d_in[8];
  const float* infw = (const float*)d_in[9];
  const float* infb = (const float*)d_in[10];
  const float* xw1  = (const float*)d_in[11];
  const float* xb1  = (const float*)d_in[12];
  const float* xw2  = (const float*)d_in[13];
  const float* xb2  = (const float*)d_in[14];
  const float* nw1  = (const float*)d_in[15];
  const float* nb1  = (const float*)d_in[16];
  const float* nw2  = (const float*)d_in[17];
  const float* nb2  = (const float*)d_in[18];

  float* out = (float*)d_out;
  float* miF = out;                  // f32 fallback: mi accumulates where h_new will go
  float* dxp = out + NNODES*HID;     // delta_x accumulates where x_new will go
  unsigned short* wsp = (unsigned short*)d_ws;
  unsigned short* miB = wsp + 118784;

  size_t need = 118784u*2u + (size_t)NNODES*HID*2u;  // weights + bf16 mi = 13.04 MB
  int mib = (ws_size >= need) ? 1 : 0;

  if (mib) {
    hipMemsetAsync(miB, 0, (size_t)NNODES*HID*2, stream);
    hipMemsetAsync(dxp, 0, (size_t)NNODES*3*4, stream);
  } else {
    hipMemsetAsync(d_out, 0, (size_t)out_size * sizeof(float), stream);
  }

  pack_kernel<<<464, 256, 0, stream>>>(ew1, ew2, xw1, nw1, nw2, wsp);

  if (mib) {
    edge_kernel<1><<<NEDGES/64, 256, 0, stream>>>(
        src, dst, ef, h, x, eb1, eb2, infw, infb, xb1, xw2, xb2,
        (const short8*)wsp, (const short8*)(wsp + 36864), (const short8*)(wsp + 53248),
        miF, miB, dxp);
    node_kernel<1><<<(NNODES + 63)/64, 256, 0, stream>>>(
        h, x, nb1, nb2,
        (const short8*)(wsp + 69632), (const short8*)(wsp + 102400), miB, out);
  } else {
    edge_kernel<0><<<NEDGES/64, 256, 0, stream>>>(
        src, dst, ef, h, x, eb1, eb2, infw, infb, xb1, xw2, xb2,
        (const short8*)wsp, (const short8*)(wsp + 36864), (const short8*)(wsp + 53248),
        miF, miB, dxp);
    node_kernel<0><<<(NNODES + 63)/64, 256, 0, stream>>>(
        h, x, nb1, nb2,
        (const short8*)(wsp + 69632), (const short8*)(wsp + 102400), miB, out);
  }
}